// Round 8
// baseline (609.950 us; speedup 1.0000x reference)
//
#include <hip/hip_runtime.h>
#include <hip/hip_bf16.h>
#include <math.h>

using bf16 = __hip_bfloat16;
typedef __attribute__((ext_vector_type(8))) short short8;
typedef __attribute__((ext_vector_type(4))) float f32x4;

#define SCALE 0.125f
#define NEGV  -1e30f
#define QS    3200            // qkv row stride: 3072 qkv cols + 96 gate cols + pad

__device__ __forceinline__ float bf2f(bf16 x) { return __bfloat162float(x); }
__device__ __forceinline__ bf16  f2bf(float x) { return __float2bfloat16(x); }
__device__ __forceinline__ float rlf(float v, int l) {
  return __int_as_float(__builtin_amdgcn_readlane(__float_as_int(v), l));
}
__device__ __forceinline__ float dot4(float4 a, float4 b) {
  return a.x * b.x + a.y * b.y + a.z * b.z + a.w * b.w;
}
__device__ __forceinline__ float sigm(float x) { return 1.0f / (1.0f + __expf(-x)); }

// async global->LDS DMA, 16B per lane; lds dest = wave-uniform base + lane*16
__device__ __forceinline__ void gload16(const bf16* g, bf16* l) {
  __builtin_amdgcn_global_load_lds(
      (const __attribute__((address_space(1))) unsigned int*)g,
      (__attribute__((address_space(3))) unsigned int*)l, 16, 0, 0);
}

// ---------------- dtype detection ------------------------------------------
__global__ void detect_mode_kernel(const void* __restrict__ bgate, int* __restrict__ flag)
{
  if (threadIdx.x == 0 && blockIdx.x == 0) {
    unsigned w = *(const unsigned*)bgate;
    flag[0] = (w == 0xC0000000u) ? 1 : 0;     // 1 = inputs are fp32
  }
}

// ---------------- batched input conversion (12 small tensors) ---------------
struct ConvArgs {
  const void* src[17];
  bf16*       dst[17];
  int         start[18];
};

__global__ __launch_bounds__(256)
void convert_all_kernel(ConvArgs a, int total, const int* __restrict__ flag)
{
  int i = blockIdx.x * 256 + threadIdx.x;
  if (i >= total) return;
  int s = 0;
  while (s < 16 && i >= a.start[s + 1]) s++;
  int off = i - a.start[s];
  if (*flag) a.dst[s][off] = f2bf(((const float*)a.src[s])[off]);
  else       a.dst[s][off] = ((const bf16*)a.src[s])[off];
}

// ---------------- tiled transpose+convert: src[K][N] -> dst[N][K] bf16 ------
__global__ __launch_bounds__(256)
void transpose_conv_kernel(const void* __restrict__ src, bf16* __restrict__ dst,
                           int K, int N, const int* __restrict__ flag)
{
  __shared__ bf16 ls[64][65];
  const int n0 = blockIdx.x * 64, k0 = blockIdx.y * 64;
  const int tid = threadIdx.x, c = tid & 63, r4 = tid >> 6;
  const bool f = (*flag != 0);
  #pragma unroll 4
  for (int r = 0; r < 16; r++) {
    int kk = r * 4 + r4;
    bf16 v = f2bf(0.f);
    if (n0 + c < N)
      v = f ? f2bf(((const float*)src)[(size_t)(k0 + kk) * N + n0 + c])
            : ((const bf16*)src)[(size_t)(k0 + kk) * N + n0 + c];
    ls[kk][c] = v;
  }
  __syncthreads();
  #pragma unroll 4
  for (int r = 0; r < 16; r++) {
    int nn = r * 4 + r4;
    if (n0 + nn < N)
      dst[(size_t)(n0 + nn) * K + k0 + c] = ls[c][nn];
  }
}

// ---------------- 64x64-tile split-K GEMM, B[K][N], fp32 atomic out ---------
__global__ __launch_bounds__(256)
void gemm64_splitk_kernel(const bf16* __restrict__ A, const bf16* __restrict__ B,
                          const bf16* __restrict__ B2, float* __restrict__ C,
                          int M, int N, int K, int msplit, int Ks)
{
  __shared__ __align__(16) bf16 As[64 * 32];
  __shared__ __align__(16) bf16 Bs[64 * 32];
  const int tid = threadIdx.x, wave = tid >> 6, lane = tid & 63;
  const int quad = lane >> 4, l16 = lane & 15;
  const int m0 = blockIdx.y * 64, n0 = blockIdx.x * 64;
  const int kb = blockIdx.z * Ks;
  const bf16* Bu = (m0 >= msplit) ? B2 : B;
  f32x4 acc[4] = {{0,0,0,0},{0,0,0,0},{0,0,0,0},{0,0,0,0}};
  const int arow = tid >> 2, akp = (tid & 3) * 8;
  const int bkr = tid >> 3, bnc = (tid & 7) * 8;

  for (int k0 = kb; k0 < kb + Ks; k0 += 32) {
    __syncthreads();
    {
      const bf16* Ap = A + (size_t)(m0 + arow) * K + k0 + akp;
      *(int4*)(void*)&As[arow * 32 + akp] = *(const int4*)(const void*)Ap;
    }
    const bf16* Bp = Bu + (size_t)(k0 + bkr) * N + n0 + bnc;
    {
      int4 raw = *(const int4*)(const void*)Bp;
      const bf16* tp = (const bf16*)&raw;
      #pragma unroll
      for (int j = 0; j < 8; j++) Bs[(bnc + j) * 32 + bkr] = tp[j];
    }
    __syncthreads();
    short8 a = *(const short8*)(const void*)&As[(wave * 16 + l16) * 32 + quad * 8];
    #pragma unroll
    for (int nt = 0; nt < 4; nt++) {
      short8 b = *(const short8*)(const void*)&Bs[(nt * 16 + l16) * 32 + quad * 8];
      acc[nt] = __builtin_amdgcn_mfma_f32_16x16x32_bf16(a, b, acc[nt], 0, 0, 0);
    }
  }

  #pragma unroll
  for (int nt = 0; nt < 4; nt++) {
    int col = n0 + nt * 16 + l16;
    if (col < N) {
      #pragma unroll
      for (int r = 0; r < 4; r++) {
        int row = m0 + wave * 16 + quad * 4 + r;
        atomicAdd(&C[(size_t)row * N + col], acc[nt][r]);
      }
    }
  }
}

// ---------------- 128x128-tile GEMM, B^T [N][K], global_load_lds staging ----
template<int TC_BF16, int ACT, int SPLIT, int GATE, int STOREF>
__global__ __launch_bounds__(256)
void gemm_bt_kernel(const bf16* __restrict__ A, const bf16* __restrict__ Bt,
                    const bf16* __restrict__ Bt2, const bf16* __restrict__ bias,
                    const bf16* __restrict__ bias2, void* __restrict__ Cv,
                    int M, int N, int K, int msplit, const int* __restrict__ flag)
{
  __shared__ __align__(16) bf16 As[128 * 32];   // As[m][k]
  __shared__ __align__(16) bf16 Bs[128 * 32];   // Bs[n][k]
  const int tid = threadIdx.x, wave = tid >> 6, lane = tid & 63;
  const int quad = lane >> 4, l16 = lane & 15;
  const int wm = (wave >> 1) * 64, wn = (wave & 1) * 64;
  const int m0 = blockIdx.y * 128, n0 = blockIdx.x * 128;
  const bf16* Bu = (SPLIT && m0 >= msplit) ? Bt2 : Bt;
  const bf16* bu = (SPLIT && m0 >= msplit) ? bias2 : bias;
  f32x4 acc[4][4];
  #pragma unroll
  for (int mt = 0; mt < 4; mt++)
    #pragma unroll
    for (int nt = 0; nt < 4; nt++) acc[mt][nt] = f32x4{0, 0, 0, 0};

  const int lr = lane >> 2, lc = (lane & 3) * 8;
  const bf16* gA0 = A  + (size_t)(m0 + wave * 32 + lr) * K + lc;
  const bf16* gA1 = gA0 + (size_t)16 * K;
  const bf16* gB0 = Bu + (size_t)(n0 + wave * 32 + lr) * K + lc;
  const bf16* gB1 = gB0 + (size_t)16 * K;
  bf16* lA0 = &As[wave * 1024];
  bf16* lA1 = &As[wave * 1024 + 512];
  bf16* lB0 = &Bs[wave * 1024];
  bf16* lB1 = &Bs[wave * 1024 + 512];

  for (int k0 = 0; k0 < K; k0 += 32) {
    __syncthreads();
    gload16(gA0 + k0, lA0);
    gload16(gA1 + k0, lA1);
    gload16(gB0 + k0, lB0);
    gload16(gB1 + k0, lB1);
    __syncthreads();

    short8 a[4], b[4];
    #pragma unroll
    for (int mt = 0; mt < 4; mt++)
      a[mt] = *(const short8*)(const void*)&As[(wm + mt * 16 + l16) * 32 + quad * 8];
    #pragma unroll
    for (int nt = 0; nt < 4; nt++)
      b[nt] = *(const short8*)(const void*)&Bs[(wn + nt * 16 + l16) * 32 + quad * 8];
    #pragma unroll
    for (int mt = 0; mt < 4; mt++)
      #pragma unroll
      for (int nt = 0; nt < 4; nt++)
        acc[mt][nt] = __builtin_amdgcn_mfma_f32_16x16x32_bf16(a[mt], b[nt], acc[mt][nt], 0, 0, 0);
  }

  const bool f32out = STOREF ? (*flag != 0) : false;
  #pragma unroll
  for (int nt = 0; nt < 4; nt++) {
    int col = n0 + wn + nt * 16 + l16;
    float bv;
    if (GATE) bv = (col >= 3072 && col < 3168) ? bf2f(bias2[col - 3072]) : 0.0f;
    else      bv = bu ? bf2f(bu[col]) : 0.0f;
    #pragma unroll
    for (int mt = 0; mt < 4; mt++) {
      #pragma unroll
      for (int r = 0; r < 4; r++) {
        int row = m0 + wm + mt * 16 + quad * 4 + r;
        float v = acc[mt][nt][r] + bv;
        if (ACT == 1) v = fmaxf(v, 0.0f);
        if (STOREF) {
          if (f32out) ((float*)Cv)[(size_t)row * N + col] = v;
          else        ((bf16*)Cv)[(size_t)row * N + col]  = f2bf(v);
        } else if (TC_BF16) {
          ((bf16*)Cv)[(size_t)row * N + col] = f2bf(v);
        } else {
          ((float*)Cv)[(size_t)row * N + col] = v;
        }
      }
    }
  }
}

// ---------------- build kb/vb ----------------------------------------------
__global__ __launch_bounds__(256)
void prep_kb_kernel(const float* __restrict__ qkv, const bf16* __restrict__ k_pos,
                    const bf16* __restrict__ v_pos, bf16* __restrict__ kbflat,
                    bf16* __restrict__ vbflat)
{
  int idx = blockIdx.x * 256 + threadIdx.x;
  if (idx >= 8 * 128 * 1024) return;
  int h = idx >> 17, rem = idx & 131071;
  int c = rem >> 10, f = rem & 1023, t = f >> 6, d = f & 63;
  int tok = c * 16 + t;
  float kv = qkv[(size_t)tok * QS + 2048 + h * 64 + d] + bf2f(k_pos[(h * 16 + t) * 64 + d]);
  float vv = qkv[(size_t)tok * QS + 2560 + h * 64 + d] + bf2f(v_pos[(h * 16 + t) * 64 + d]);
  kbflat[idx] = f2bf(kv);
  vbflat[idx] = f2bf(vv);
}

// ---------------- concat mem token (+ layer2 bias) --------------------------
__global__ __launch_bounds__(256)
void concat_kernel(const float* __restrict__ ckpre, const float* __restrict__ cvpre,
                   const bf16* __restrict__ mem_ck, const bf16* __restrict__ mem_cv,
                   const bf16* __restrict__ k_cb2, const bf16* __restrict__ v_cb2,
                   float* __restrict__ ck, float* __restrict__ cv)
{
  int idx = blockIdx.x * 256 + threadIdx.x;
  if (idx >= 8 * 129 * 64) return;
  int h = idx / (129 * 64), r = (idx >> 6) % 129, d = idx & 63;
  if (r == 0) {
    ck[idx] = bf2f(mem_ck[h * 64 + d]);
    cv[idx] = bf2f(mem_cv[h * 64 + d]);
  } else {
    ck[idx] = ckpre[((size_t)h * 128 + r - 1) * 64 + d] + bf2f(k_cb2[d]);
    cv[idx] = cvpre[((size_t)h * 128 + r - 1) * 64 + d] + bf2f(v_cb2[d]);
  }
}

// ---------------- compression attention + importance top-8 ------------------
__global__ __launch_bounds__(256)
void compress_attn_kernel(const float* __restrict__ qkv, const float* __restrict__ ck,
                          const float* __restrict__ cv,
                          float* __restrict__ outpre, int* __restrict__ sel)
{
  __shared__ __align__(16) float qs[4][4][64];   // [wave][g][d]
  const int tid = threadIdx.x, w = tid >> 6, lane = tid & 63;
  const int R = blockIdx.x * 4 + w, h = R >> 11, i = R & 2047;

  #pragma unroll
  for (int g = 0; g < 4; g++)
    qs[w][g][lane] = qkv[(size_t)i * QS + (h * 4 + g) * 64 + lane];  // pre-rope q
  __syncthreads();

  const int jv = i >> 4;
  bool jin2 = (lane == 0);
  bool v0 = (lane == 0 || lane <= jv);
  bool v1 = (lane + 64 <= jv);
  bool v2 = jin2 && (128 <= jv);

  const float* kh = ck + (size_t)h * 129 * 64;
  const float4* k0 = (const float4*)(kh + lane * 64);
  const float4* k1 = (const float4*)(kh + (lane + 64) * 64);
  const float4* k2 = (const float4*)(kh + (jin2 ? 128 : 0) * 64);
  const float4* q4[4];
  #pragma unroll
  for (int g = 0; g < 4; g++) q4[g] = (const float4*)&qs[w][g][0];

  float d0[4] = {0,0,0,0}, d1[4] = {0,0,0,0}, d2[4] = {0,0,0,0};
  #pragma unroll
  for (int t = 0; t < 16; t++) {
    float4 a = k0[t], b = k1[t], c = k2[t];
    #pragma unroll
    for (int g = 0; g < 4; g++) {
      float4 qv = q4[g][t];
      d0[g] += dot4(qv, a);
      d1[g] += dot4(qv, b);
      d2[g] += dot4(qv, c);
    }
  }

  float sc0[4], sc1[4], sc2[4];
  #pragma unroll
  for (int g = 0; g < 4; g++) {
    sc0[g] = v0 ? d0[g] * SCALE : NEGV;
    sc1[g] = v1 ? d1[g] * SCALE : NEGV;
    sc2[g] = jin2 ? (v2 ? d2[g] * SCALE : NEGV) : -3.0e38f;
  }
  float imp0 = (sc0[0] + sc0[1] + sc0[2] + sc0[3]) * 0.25f;
  float imp1 = (sc1[0] + sc1[1] + sc1[2] + sc1[3]) * 0.25f;
  float imp2 = jin2 ? (sc2[0] + sc2[1] + sc2[2] + sc2[3]) * 0.25f : -3.0e38f;

  float p0[4], p1[4], p2[4];
  #pragma unroll
  for (int g = 0; g < 4; g++) {
    float mx = fmaxf(sc0[g], fmaxf(sc1[g], sc2[g]));
    for (int off = 32; off; off >>= 1) mx = fmaxf(mx, __shfl_xor(mx, off));
    float e0 = __expf(sc0[g] - mx), e1 = __expf(sc1[g] - mx);
    float e2 = jin2 ? __expf(sc2[g] - mx) : 0.0f;
    float sm = e0 + e1 + e2;
    for (int off = 32; off; off >>= 1) sm += __shfl_xor(sm, off);
    float inv = 1.0f / sm;
    p0[g] = e0 * inv; p1[g] = e1 * inv; p2[g] = e2 * inv;
  }

  const float* vh = cv + (size_t)h * 129 * 64 + lane;
  float o[4] = {0,0,0,0};
  #pragma unroll 8
  for (int jj = 0; jj < 64; jj++) {
    float vv = vh[jj * 64];
    #pragma unroll
    for (int g = 0; g < 4; g++) o[g] = fmaf(rlf(p0[g], jj), vv, o[g]);
  }
  #pragma unroll 8
  for (int jj = 0; jj < 64; jj++) {
    float vv = vh[(64 + jj) * 64];
    #pragma unroll
    for (int g = 0; g < 4; g++) o[g] = fmaf(rlf(p1[g], jj), vv, o[g]);
  }
  {
    float vv = vh[128 * 64];
    #pragma unroll
    for (int g = 0; g < 4; g++) o[g] = fmaf(rlf(p2[g], 0), vv, o[g]);
  }

  #pragma unroll
  for (int g = 0; g < 4; g++) {
    int hq = h * 4 + g;
    float g0 = sigm(qkv[(size_t)i * QS + 3072 + hq * 3 + 0]);
    outpre[(size_t)i * 2048 + hq * 64 + lane] = g0 * o[g];  // first writer
  }

  float iv0 = (lane == 0) ? -1000.0f : imp0;
  float iv1 = imp1;
  float iv2 = imp2;
  float mx = fmaxf(iv0, fmaxf(iv1, iv2));
  for (int off = 32; off; off >>= 1) mx = fmaxf(mx, __shfl_xor(mx, off));
  float e0 = __expf(iv0 - mx), e1 = __expf(iv1 - mx);
  float e2 = jin2 ? __expf(iv2 - mx) : 0.0f;
  float sm = e0 + e1 + e2;
  for (int off = 32; off; off >>= 1) sm += __shfl_xor(sm, off);
  float inv = 1.0f / sm;
  float q0 = (lane >= 1) ? e0 * inv : -1.0f;
  float q1 = e1 * inv;
  float q2 = jin2 ? e2 * inv : -1.0f;

  for (int s = 0; s < 8; s++) {
    float bv = q0; int bj = lane;
    if (q1 > bv) { bv = q1; bj = lane + 64; }
    if (q2 > bv) { bv = q2; bj = lane + 128; }
    for (int off = 32; off; off >>= 1) {
      float ov = __shfl_xor(bv, off); int oj = __shfl_xor(bj, off);
      if (ov > bv || (ov == bv && oj < bj)) { bv = ov; bj = oj; }
    }
    if (lane == 0) sel[((size_t)h * 2048 + i) * 8 + s] = (bv > 1e-10f) ? (bj - 1) : -1;
    if (bj == lane)            q0 = -1.0f;
    else if (bj == lane + 64)  q1 = -1.0f;
    else if (bj == lane + 128) q2 = -1.0f;
  }
}

// ---------------- rope in-place + bf16 K arena ------------------------------
// kb16 layout: [h][tok][64] bf16 (roped k), for MFMA B-fragments in fs_attn.
__global__ __launch_bounds__(256)
void rope_kernel(float* __restrict__ qkv, bf16* __restrict__ kb16)
{
  int idx = blockIdx.x * 256 + threadIdx.x;      // (i*40 + hh)*32 + m
  if (idx >= 2048 * 40 * 32) return;
  int m = idx & 31, hh = (idx >> 5) % 40, i = idx / 1280;
  int col = (hh < 32) ? hh * 64 + 2 * m : 2048 + (hh - 32) * 64 + 2 * m;
  float* p = qkv + (size_t)i * QS + col;
  float x1 = p[0], x2 = p[1];
  float inv = exp2f(-0.41524101186092029f * (float)m);   // 10000^(-2m/64)
  float ang = (float)i * inv;
  float s, c;
  sincosf(ang, &s, &c);
  float r0 = x1 * c - x2 * s;
  float r1 = x1 * s + x2 * c;
  p[0] = r0;
  p[1] = r1;
  if (hh >= 32) {
    bf16* kp = kb16 + (((size_t)(hh - 32) * 2048 + i) * 64 + 2 * m);
    kp[0] = f2bf(r0);
    kp[1] = f2bf(r1);
  }
}

// ---------------- fused fine + sliding attention (MFMA scores) --------------
// One wave per (h,i). Key space j in [0,224): tiles 0..7 = selected blocks,
// tile 8 = own block (causal within), tiles 9..13 = sliding rows i-64..i
// (j=208 is the self key; j>208 masked). Scores via 16x16x32 bf16 MFMA
// (q rows 0..3 = g heads, rows 4..15 garbage/ignored). Gates folded into P.
__global__ __launch_bounds__(256)
void fs_attn_kernel(const float* __restrict__ qkv, const bf16* __restrict__ kb16,
                    const int* __restrict__ sel, const float* __restrict__ outpre,
                    bf16* __restrict__ outpre_b)
{
  __shared__ __align__(16) bf16  qls[4][16][64];   // [wave][m][d], rows 4..15 unwritten
  __shared__ __align__(16) float pls[4][224][4];   // [wave][j][g] gated probabilities
  const int tid = threadIdx.x, w = tid >> 6, lane = tid & 63;
  const int l16 = lane & 15, quad = lane >> 4;
  const int R = blockIdx.x * 4 + w, h = R >> 11, i = R & 2047;

  // stage roped q as bf16 (intra-wave LDS, no barrier needed)
  #pragma unroll
  for (int g = 0; g < 4; g++)
    qls[w][g][lane] = f2bf(qkv[(size_t)i * QS + (h * 4 + g) * 64 + lane]);

  short8 aq0 = *(const short8*)(const void*)&qls[w][l16][quad * 8];
  short8 aq1 = *(const short8*)(const void*)&qls[w][l16][32 + quad * 8];

  int blk[8];
  #pragma unroll
  for (int s = 0; s < 8; s++)
    blk[s] = sel[((size_t)h * 2048 + i) * 8 + s];   // wave-uniform

  // ---- score pass: 14 j-tiles x 2 MFMA ----
  const bf16* kh = kb16 + (size_t)h * 2048 * 64;
  f32x4 sc[14];
  #pragma unroll
  for (int jt = 0; jt < 14; jt++) {
    int rbase;
    if (jt < 8)       rbase = (blk[jt] < 0 ? 0 : blk[jt]) * 16;
    else if (jt == 8) rbase = (i >> 4) * 16;
    else              rbase = i - 208 + jt * 16;
    int row = rbase + l16;
    row = min(max(row, 0), 2047);
    const bf16* kp = kh + (size_t)row * 64 + quad * 8;
    short8 b0 = *(const short8*)(const void*)kp;
    short8 b1 = *(const short8*)(const void*)(kp + 32);
    f32x4 z = {0, 0, 0, 0};
    z = __builtin_amdgcn_mfma_f32_16x16x32_bf16(aq0, b0, z, 0, 0, 0);
    z = __builtin_amdgcn_mfma_f32_16x16x32_bf16(aq1, b1, z, 0, 0, 0);
    sc[jt] = z;
  }

  // ---- masks + scale (meaningful on lanes 0..15 = C rows g 0..3) ----
  #pragma unroll
  for (int jt = 0; jt < 14; jt++) {
    bool valid;
    if (jt < 8)       valid = (blk[jt] >= 0);
    else if (jt == 8) valid = (l16 <= (i & 15));
    else {
      int j = jt * 16 + l16;
      valid = (j <= 208) && (i - 208 + j >= 0);
    }
    #pragma unroll
    for (int g = 0; g < 4; g++)
      sc[jt][g] = valid ? sc[jt][g] * SCALE : -3.0e38f;
  }

  // gates (wave-uniform scalar loads)
  float g1v[4], g2v[4];
  #pragma unroll
  for (int g = 0; g < 4; g++) {
    g1v[g] = sigm(qkv[(size_t)i * QS + 3072 + (h * 4 + g) * 3 + 1]);
    g2v[g] = sigm(qkv[(size_t)i * QS + 3072 + (h * 4 + g) * 3 + 2]);
  }

  // ---- two softmaxes (fine: tiles 0..8, sliding: 9..13), gates folded ----
  #pragma unroll
  for (int g = 0; g < 4; g++) {
    float m1 = -3.0e38f;
    #pragma unroll
    for (int jt = 0; jt < 9; jt++) m1 = fmaxf(m1, sc[jt][g]);
    #pragma unroll
    for (int off = 1; off < 16; off <<= 1) m1 = fmaxf(m1, __shfl_xor(m1, off));
    float s1 = 0;
    #pragma unroll
    for (int jt = 0; jt < 9; jt++) { float e = __expf(sc[jt][g] - m1); sc[jt][g] = e; s1 += e; }
    #pragma unroll
    for (int off = 1; off < 16; off <<= 1) s1 += __shfl_xor(s1, off);
    float f1 = g1v[g] / s1;
    #pragma unroll
    for (int jt = 0; jt < 9; jt++) sc[jt][g] *= f1;

    float m2 = -3.0e38f;
    #pragma unroll
    for (int jt = 9; jt < 14; jt++) m2 = fmaxf(m2, sc[jt][g]);
    #pragma unroll
    for (int off = 1; off < 16; off <<= 1) m2 = fmaxf(m2, __shfl_xor(m2, off));
    float s2 = 0;
    #pragma unroll
    for (int jt = 9; jt < 14; jt++) { float e = __expf(sc[jt][g] - m2); sc[jt][g] = e; s2 += e; }
    #pragma unroll
    for (int off = 1; off < 16; off <<= 1) s2 += __shfl_xor(s2, off);
    float f2 = g2v[g] / s2;
    #pragma unroll
    for (int jt = 9; jt < 14; jt++) sc[jt][g] *= f2;
  }

  // ---- publish P (quad0 holds the real rows) ----
  if (quad == 0) {
    #pragma unroll
    for (int jt = 0; jt < 14; jt++) {
      float4 pv = {sc[jt][0], sc[jt][1], sc[jt][2], sc[jt][3]};
      *(float4*)(void*)&pls[w][jt * 16 + l16][0] = pv;
    }
  }

  // ---- PV pass: broadcast P from LDS, coalesced V rows, no readlanes ----
  const float* vb = qkv + 2560 + h * 64 + lane;
  float o[4] = {0, 0, 0, 0};
  #pragma unroll
  for (int jt = 0; jt < 14; jt++) {
    if (jt < 8 && blk[jt] < 0) continue;          // wave-uniform skip (P would be 0)
    int rbase;
    if (jt < 8)       rbase = blk[jt] * 16;
    else if (jt == 8) rbase = (i >> 4) * 16;
    else              rbase = i - 208 + jt * 16;
    #pragma unroll 4
    for (int t = 0; t < 16; t++) {
      int row = rbase + t;
      row = min(max(row, 0), 2047);               // masked j have P==0
      float4 p = *(const float4*)(const void*)&pls[w][jt * 16 + t][0];
      float vv = vb[(size_t)row * QS];
      o[0] = fmaf(p.x, vv, o[0]);
      o[1] = fmaf(p.y, vv, o[1]);
      o[2] = fmaf(p.z, vv, o[2]);
      o[3] = fmaf(p.w, vv, o[3]);
    }
  }

  // ---- epilogue: add compress term, store bf16 ----
  #pragma unroll
  for (int g = 0; g < 4; g++) {
    size_t oidx = (size_t)i * 2048 + (h * 4 + g) * 64 + lane;
    outpre_b[oidx] = f2bf(outpre[oidx] + o[g]);
  }
}

// ---------------------------------------------------------------------------
extern "C" void kernel_launch(void* const* d_in, const int* in_sizes, int n_in,
                              void* d_out, int out_size, void* d_ws, size_t ws_size,
                              hipStream_t stream)
{
  char* ws = (char*)d_ws;
  size_t off = 0;
  auto alloc = [&](size_t bytes) -> char* {
    char* p = ws + off; off = (off + bytes + 255) & ~(size_t)255; return p;
  };

  int* flag = (int*)alloc(256);
  bf16* inb[17];
  for (int i = 0; i < 17; i++) {
    if (i == 1 || i == 4 || i == 8 || i == 14 || i == 16) { inb[i] = nullptr; continue; }
    inb[i] = (bf16*)alloc((size_t)in_sizes[i] * sizeof(bf16));
  }
  bf16* w_qkvT = (bf16*)alloc(3200ull * 2048 * 2);   // rows 0..3071 qkv^T, 3072..3167 gate^T
  bf16* k_cw1T = (bf16*)alloc(1024ull * 1024 * 2);
  bf16* v_cw1T = (bf16*)alloc(1024ull * 1024 * 2);
  bf16* w_outT = (bf16*)alloc(2048ull * 2048 * 2);

  float* qkv      = (float*)alloc(2048ull * QS * 4);    // qkv + gate logits
  float* outpre   = (float*)alloc(2048ull * 2048 * 4);  // fp32 compress term
  bf16*  kvb      = (bf16*)alloc(2048ull * 1024 * 2);   // [kbflat; vbflat]; reused as outpre_b
  bf16*  hid      = (bf16*)alloc(2048ull * 1024 * 2);   // [hidk; hidv]
  float* ckcvpre  = (float*)alloc(2048ull * 64 * 4);    // [ckpre; cvpre] (split-K atomic)
  float* ckb      = (float*)alloc(8ull * 129 * 64 * 4);
  float* cvb      = (float*)alloc(8ull * 129 * 64 * 4);
  int*   sel      = (int*)alloc(8ull * 2048 * 8 * 4);
  bf16*  kb16     = (bf16*)alloc(8ull * 2048 * 64 * 2); // roped K, bf16, [h][tok][d]
  bf16*  outpre_b = kvb;                                // kvb dead after MLP1

  const bf16 *xb = inb[0], *k_posb = inb[2], *v_posb = inb[3],
             *k_cb1b = inb[5], *k_cw2b = inb[6], *k_cb2b = inb[7],
             *v_cb1b = inb[9], *v_cw2b = inb[10], *v_cb2b = inb[11],
             *mem_ckb = inb[12], *mem_cvb = inb[13], *b_gateb = inb[15];

  detect_mode_kernel<<<1, 64, 0, stream>>>(d_in[15], flag);

  ConvArgs ca;
  int total = 0, nseg = 0;
  for (int i = 0; i < 17; i++) {
    if (i == 1 || i == 4 || i == 8 || i == 14 || i == 16) continue;
    ca.src[nseg] = d_in[i];
    ca.dst[nseg] = inb[i];
    ca.start[nseg] = total;
    total += in_sizes[i];
    nseg++;
  }
  for (int s = nseg; s <= 17; s++) ca.start[s] = total;
  convert_all_kernel<<<(total + 255) / 256, 256, 0, stream>>>(ca, total, flag);

  transpose_conv_kernel<<<dim3(48, 32), 256, 0, stream>>>(d_in[1],  w_qkvT, 2048, 3072, flag);
  transpose_conv_kernel<<<dim3(2, 32),  256, 0, stream>>>(d_in[14], w_qkvT + 3072ull * 2048, 2048, 96, flag);
  transpose_conv_kernel<<<dim3(16, 16), 256, 0, stream>>>(d_in[4],  k_cw1T, 1024, 1024, flag);
  transpose_conv_kernel<<<dim3(16, 16), 256, 0, stream>>>(d_in[8],  v_cw1T, 1024, 1024, flag);
  transpose_conv_kernel<<<dim3(32, 32), 256, 0, stream>>>(d_in[16], w_outT, 2048, 2048, flag);
  hipMemsetAsync(ckcvpre, 0, 2048ull * 64 * 4, stream);

  // qkv + gate logits = x @ [w_qkv | w_gate]   (2048 x 3200 x 2048)
  gemm_bt_kernel<0,0,0,1,0><<<dim3(25, 16), 256, 0, stream>>>(
      xb, w_qkvT, nullptr, nullptr, b_gateb, qkv, 2048, QS, 2048, 0, nullptr);
  prep_kb_kernel<<<4096, 256, 0, stream>>>(qkv, k_posb, v_posb, kvb, kvb + 1024 * 1024);
  gemm_bt_kernel<1,1,1,0,0><<<dim3(8, 16), 256, 0, stream>>>(
      kvb, k_cw1T, v_cw1T, k_cb1b, v_cb1b, hid, 2048, 1024, 1024, 1024, nullptr);
  gemm64_splitk_kernel<<<dim3(1, 32, 4), 256, 0, stream>>>(
      hid, k_cw2b, v_cw2b, ckcvpre, 2048, 64, 1024, 1024, 256);
  concat_kernel<<<259, 256, 0, stream>>>(ckcvpre, ckcvpre + 1024 * 64,
                                         mem_ckb, mem_cvb, k_cb2b, v_cb2b, ckb, cvb);
  compress_attn_kernel<<<4096, 256, 0, stream>>>(qkv, ckb, cvb, outpre, sel);
  rope_kernel<<<10240, 256, 0, stream>>>(qkv, kb16);
  fs_attn_kernel<<<4096, 256, 0, stream>>>(qkv, kb16, sel, outpre, outpre_b);
  gemm_bt_kernel<0,0,0,0,1><<<dim3(16, 16), 256, 0, stream>>>(
      outpre_b, w_outT, nullptr, nullptr, nullptr, d_out, 2048, 2048, 2048, 0, flag);
}